// Round 2
// baseline (288.110 us; speedup 1.0000x reference)
//
#include <hip/hip_runtime.h>
#include <stdint.h>

#define D_MODEL 1024
#define NHEADS 16
#define HDIM 64
#define BATCH 2
#define SEQ 2048
#define MTOK (BATCH*SEQ)

typedef unsigned short u16;
typedef __attribute__((ext_vector_type(8))) __bf16 bf16x8;
typedef __attribute__((ext_vector_type(8))) unsigned short u16x8;
typedef __attribute__((ext_vector_type(4))) float f32x4;

__device__ __forceinline__ u16 f2bf(float f) {
  union { float f; uint32_t u; } v; v.f = f;
  uint32_t u = v.u;
  u += 0x7fffu + ((u >> 16) & 1u);   // RNE
  return (u16)(u >> 16);
}

__device__ __forceinline__ u16 f2bf_hw(float f) {
  return __builtin_bit_cast(u16, (__bf16)f);   // v_cvt, RNE
}

__device__ __forceinline__ void async16(u16* lds, const u16* g) {
  __builtin_amdgcn_global_load_lds(
      (__attribute__((address_space(1))) void*)(u16*)g,
      (__attribute__((address_space(3))) void*)lds,
      16, 0, 0);
}

// ---------------- cast f32 -> bf16 (vectorized) ----------------
__global__ __launch_bounds__(256) void cast_bf16_kernel(
    const float* __restrict__ in, u16* __restrict__ out, int n8)
{
  int i = blockIdx.x * 256 + threadIdx.x;
  if (i >= n8) return;
  const float4* p = (const float4*)(in + (size_t)i * 8);
  float4 a = p[0], b = p[1];
  u16x8 r;
  r[0]=f2bf(a.x); r[1]=f2bf(a.y); r[2]=f2bf(a.z); r[3]=f2bf(a.w);
  r[4]=f2bf(b.x); r[5]=f2bf(b.y); r[6]=f2bf(b.z); r[7]=f2bf(b.w);
  *(u16x8*)(out + (size_t)i * 8) = r;
}

// ---------------- transpose+cast f32 [R][C] -> bf16 [C][R] ----------------
__global__ __launch_bounds__(256) void transpose_cast_kernel(
    const float* __restrict__ in, u16* __restrict__ out, int R, int C)
{
  __shared__ float tile[32][33];
  int nCB = C >> 5;
  int bc = blockIdx.x % nCB, br = blockIdx.x / nCB;
  int r0 = br * 32, c0 = bc * 32;
  int tx = threadIdx.x & 31, ty = threadIdx.x >> 5;
#pragma unroll
  for (int i = 0; i < 4; ++i)
    tile[ty + i*8][tx] = in[(size_t)(r0 + ty + i*8) * C + c0 + tx];
  __syncthreads();
#pragma unroll
  for (int i = 0; i < 4; ++i)
    out[(size_t)(c0 + ty + i*8) * R + r0 + tx] = f2bf(tile[tx][ty + i*8]);
}

// ---------------- transpose bf16 V [bh][2048][64] -> [bh][64][2048] ----------------
__global__ __launch_bounds__(256) void transpose_v_kernel(
    const u16* __restrict__ vb, u16* __restrict__ vt)
{
  __shared__ u16 tile[32][34];
  int b = blockIdx.x >> 7;      // 0..31 (b*H+h)
  int t = blockIdx.x & 127;
  int br = t >> 1, bc = t & 1;
  int r0 = br * 32, c0 = bc * 32;
  const u16* in = vb + (size_t)b * SEQ * HDIM;
  u16* out = vt + (size_t)b * SEQ * HDIM;
  int tx = threadIdx.x & 31, ty = threadIdx.x >> 5;
#pragma unroll
  for (int i = 0; i < 4; ++i)
    tile[ty + i*8][tx] = in[(size_t)(r0 + ty + i*8) * HDIM + c0 + tx];
  __syncthreads();
#pragma unroll
  for (int i = 0; i < 4; ++i)
    out[(size_t)(c0 + ty + i*8) * SEQ + r0 + tx] = tile[tx][ty + i*8];
}

// ---------------- NT GEMM: C[M][N] = A[M][K](bf16) * Bt[N][K](bf16)^T + bias ----------------
// EPI=0: QKV epilogue -> scatter q(*scale)/k/v into [B,H,N,Hd] bf16
// EPI=1: f32 out
template <int EPI>
__global__ __launch_bounds__(256) void gemm_bt_kernel(
    const u16* __restrict__ A, const u16* __restrict__ Bt,
    const float* __restrict__ bias,
    float* __restrict__ outF,
    u16* __restrict__ qb, u16* __restrict__ kb, u16* __restrict__ vb,
    int M, int Nn, int K)
{
  __shared__ alignas(16) u16 As[128 * 64];
  __shared__ alignas(16) u16 Bs[128 * 64];

  const int tid = threadIdx.x;
  const int wid = tid >> 6, lane = tid & 63;
  const int col = lane & 15, kg = lane >> 4;

  const int nTN = Nn >> 7;
  int bidx = blockIdx.x;
  {
    int cpx = gridDim.x >> 3;     // grid % 8 == 0 for all our launches
    bidx = (bidx & 7) * cpx + (bidx >> 3);
  }
  const int tile_m = (bidx / nTN) << 7;
  const int tile_n = (bidx % nTN) << 7;
  const int wm = (wid >> 1) << 6, wn = (wid & 1) << 6;

  f32x4 acc[4][4] = {};

  const int sr = tid >> 3;          // 0..31
  const int sc = (tid & 7) << 3;    // 0..56

  for (int kt = 0; kt < K; kt += 64) {
    __syncthreads();
#pragma unroll
    for (int i = 0; i < 4; ++i)
      async16(&As[(i*32 + sr) * 64 + sc],
              A + (size_t)(tile_m + i*32 + sr) * K + kt + sc);
#pragma unroll
    for (int i = 0; i < 4; ++i)
      async16(&Bs[(i*32 + sr) * 64 + sc],
              Bt + (size_t)(tile_n + i*32 + sr) * K + kt + sc);
    __syncthreads();

#pragma unroll
    for (int ks = 0; ks < 2; ++ks) {
      bf16x8 af[4], bfv[4];
#pragma unroll
      for (int i = 0; i < 4; ++i)
        af[i] = *(const bf16x8*)&As[(wm + i*16 + col) * 64 + ks*32 + kg*8];
#pragma unroll
      for (int i = 0; i < 4; ++i)
        bfv[i] = *(const bf16x8*)&Bs[(wn + i*16 + col) * 64 + ks*32 + kg*8];
#pragma unroll
      for (int i = 0; i < 4; ++i)
#pragma unroll
        for (int j = 0; j < 4; ++j)
          acc[i][j] = __builtin_amdgcn_mfma_f32_16x16x32_bf16(af[i], bfv[j], acc[i][j], 0, 0, 0);
    }
  }

  // epilogue: lane holds C[tile_m+wm+i*16+kg*4+j][tile_n+wn+jn*16+col]
#pragma unroll
  for (int i = 0; i < 4; ++i) {
#pragma unroll
    for (int jn = 0; jn < 4; ++jn) {
      const int gcol = tile_n + wn + jn*16 + col;
      const float bv = bias[gcol];
#pragma unroll
      for (int j = 0; j < 4; ++j) {
        const int grow = tile_m + wm + i*16 + kg*4 + j;
        float val = acc[i][jn][j] + bv;
        if (EPI == 1) {
          outF[(size_t)grow * Nn + gcol] = val;
        } else {
          int btok = grow >> 11, tok = grow & 2047;
          int which = gcol >> 10, f = gcol & 1023;
          int h = f >> 6, hd = f & 63;
          size_t dst = ((size_t)(btok * NHEADS + h) * SEQ + tok) * HDIM + hd;
          // fold scale = Hd^-0.5 * log2(e) into Q (softmax runs in exp2 domain)
          if (which == 0)      qb[dst] = f2bf(val * 0.18033688f);
          else if (which == 1) kb[dst] = f2bf(val);
          else                 vb[dst] = f2bf(val);
        }
      }
    }
  }
}

// ---------------- flash attention: barrier-free, direct-global K/V ----------------
// block = (b*H+h, q-tile of 128); 4 independent waves x 32 q-rows; KV tile = 64.
// K/V fragments read straight from global (L1/L2-resident); only P goes through
// per-wave LDS. Softmax in exp2 domain (scale pre-folded into Q).
__global__ __launch_bounds__(256, 4) void attn_kernel(
    const u16* __restrict__ qb, const u16* __restrict__ kb,
    const u16* __restrict__ vt, u16* __restrict__ ao)
{
  __shared__ alignas(16) u16 Pl[4][32 * 72];   // per-wave P [32 q][64 kv] pitch 72

  const int tid = threadIdx.x, wid = tid >> 6, lane = tid & 63;
  const int col = lane & 15, kg = lane >> 4;

  int bidx = blockIdx.x;
  bidx = (bidx & 7) * 64 + (bidx >> 3);   // XCD swizzle (grid 512)
  const int bh = bidx >> 4;     // 0..31
  const int qt = bidx & 15;

  const u16* Qh = qb + (size_t)bh * SEQ * HDIM;
  const u16* Kh = kb + (size_t)bh * SEQ * HDIM;
  const u16* Vh = vt + (size_t)bh * SEQ * HDIM;  // [64][2048]

  const int q0 = qt * 128 + wid * 32;
  bf16x8 qf[2][2];
#pragma unroll
  for (int mf = 0; mf < 2; ++mf)
#pragma unroll
    for (int ks = 0; ks < 2; ++ks)
      qf[mf][ks] = *(const bf16x8*)(Qh + (size_t)(q0 + mf*16 + col) * HDIM + ks*32 + kg*8);

  float m_run[2][4], l_run[2][4];
  f32x4 o[2][4] = {};
#pragma unroll
  for (int mf = 0; mf < 2; ++mf)
#pragma unroll
    for (int j = 0; j < 4; ++j) { m_run[mf][j] = -1e30f; l_run[mf][j] = 0.f; }

  u16* Pw = Pl[wid];

  for (int t = 0; t < 32; ++t) {
    const u16* Kt = Kh + (size_t)t * 64 * HDIM;

    // S = Q K^T  (K fragments direct from global)
    f32x4 s[2][4] = {};
#pragma unroll
    for (int ks = 0; ks < 2; ++ks) {
#pragma unroll
      for (int nf = 0; nf < 4; ++nf) {
        bf16x8 kf = *(const bf16x8*)(Kt + (size_t)(nf*16 + col) * HDIM + ks*32 + kg*8);
        s[0][nf] = __builtin_amdgcn_mfma_f32_16x16x32_bf16(qf[0][ks], kf, s[0][nf], 0, 0, 0);
        s[1][nf] = __builtin_amdgcn_mfma_f32_16x16x32_bf16(qf[1][ks], kf, s[1][nf], 0, 0, 0);
      }
    }

    // online softmax (exp2 domain); lane owns rows kg*4+j, cols via 16-lane shfl
#pragma unroll
    for (int mf = 0; mf < 2; ++mf) {
#pragma unroll
      for (int j = 0; j < 4; ++j) {
        float mx = s[mf][0][j];
#pragma unroll
        for (int nf = 1; nf < 4; ++nf) mx = fmaxf(mx, s[mf][nf][j]);
        mx = fmaxf(mx, __shfl_xor(mx, 1));
        mx = fmaxf(mx, __shfl_xor(mx, 2));
        mx = fmaxf(mx, __shfl_xor(mx, 4));
        mx = fmaxf(mx, __shfl_xor(mx, 8));
        float mo = m_run[mf][j];
        float mn = fmaxf(mo, mx);
        float al = __builtin_amdgcn_exp2f(mo - mn);
        m_run[mf][j] = mn;
        float sum = 0.f;
#pragma unroll
        for (int nf = 0; nf < 4; ++nf) {
          float p = __builtin_amdgcn_exp2f(s[mf][nf][j] - mn);
          s[mf][nf][j] = p;
          sum += p;
        }
        sum += __shfl_xor(sum, 1);
        sum += __shfl_xor(sum, 2);
        sum += __shfl_xor(sum, 4);
        sum += __shfl_xor(sum, 8);
        l_run[mf][j] = l_run[mf][j] * al + sum;
#pragma unroll
        for (int hf = 0; hf < 4; ++hf) o[mf][hf][j] *= al;
      }
    }

    // P -> per-wave LDS (bf16), A-frag layout
#pragma unroll
    for (int mf = 0; mf < 2; ++mf)
#pragma unroll
      for (int j = 0; j < 4; ++j)
#pragma unroll
        for (int nf = 0; nf < 4; ++nf)
          Pw[(mf*16 + kg*4 + j) * 72 + nf*16 + col] = f2bf_hw(s[mf][nf][j]);

    // O += P V  (V fragments direct from global V^T)
#pragma unroll
    for (int ks = 0; ks < 2; ++ks) {
      bf16x8 pa0 = *(const bf16x8*)&Pw[(col) * 72 + ks*32 + kg*8];
      bf16x8 pa1 = *(const bf16x8*)&Pw[(16 + col) * 72 + ks*32 + kg*8];
#pragma unroll
      for (int hf = 0; hf < 4; ++hf) {
        bf16x8 vf = *(const bf16x8*)(Vh + (size_t)(hf*16 + col) * SEQ + t*64 + ks*32 + kg*8);
        o[0][hf] = __builtin_amdgcn_mfma_f32_16x16x32_bf16(pa0, vf, o[0][hf], 0, 0, 0);
        o[1][hf] = __builtin_amdgcn_mfma_f32_16x16x32_bf16(pa1, vf, o[1][hf], 0, 0, 0);
      }
    }
  }

  // epilogue: O/l -> ao[token][h*64+hd] bf16
  const int bb = bh >> 4, h = bh & 15;
#pragma unroll
  for (int mf = 0; mf < 2; ++mf)
#pragma unroll
    for (int hf = 0; hf < 4; ++hf)
#pragma unroll
      for (int j = 0; j < 4; ++j) {
        int nrow = q0 + mf*16 + kg*4 + j;
        int feat = h*64 + hf*16 + col;
        float val = o[mf][hf][j] / l_run[mf][j];
        ao[(size_t)(bb * SEQ + nrow) * D_MODEL + feat] = f2bf(val);
      }
}

extern "C" void kernel_launch(void* const* d_in, const int* in_sizes, int n_in,
                              void* d_out, int out_size, void* d_ws, size_t ws_size,
                              hipStream_t stream)
{
  const float* x     = (const float*)d_in[0];
  const float* w_qkv = (const float*)d_in[1];
  const float* b_qkv = (const float*)d_in[2];
  const float* w_out = (const float*)d_in[3];
  const float* b_out = (const float*)d_in[4];
  float* out = (float*)d_out;
  (void)in_sizes; (void)n_in; (void)out_size; (void)ws_size;

  char* ws = (char*)d_ws;
  u16* x_bf   = (u16*)(ws);                        // 8 MB  [4096][1024]
  u16* wqkv_t = (u16*)(ws + (size_t)( 8 << 20));   // 6 MB  [3072][1024]
  u16* wout_t = (u16*)(ws + (size_t)(14 << 20));   // 2 MB  [1024][1024]
  u16* qb     = (u16*)(ws + (size_t)(16 << 20));   // 8 MB  [32][2048][64]
  u16* kb     = (u16*)(ws + (size_t)(24 << 20));   // 8 MB
  u16* vb     = (u16*)(ws + (size_t)(32 << 20));   // 8 MB
  u16* vt     = (u16*)(ws + (size_t)(40 << 20));   // 8 MB  [32][64][2048]
  u16* ao     = (u16*)(ws + (size_t)(48 << 20));   // 8 MB  [4096][1024]

  cast_bf16_kernel<<<2048, 256, 0, stream>>>(x, x_bf, (MTOK * D_MODEL) / 8);
  transpose_cast_kernel<<<(1024/32)*(3072/32), 256, 0, stream>>>(w_qkv, wqkv_t, 1024, 3072);
  transpose_cast_kernel<<<(1024/32)*(1024/32), 256, 0, stream>>>(w_out, wout_t, 1024, 1024);

  gemm_bt_kernel<0><<<(MTOK/128)*(3072/128), 256, 0, stream>>>(
      x_bf, wqkv_t, b_qkv, nullptr, qb, kb, vb, MTOK, 3072, 1024);

  transpose_v_kernel<<<32*128, 256, 0, stream>>>(vb, vt);

  attn_kernel<<<32*16, 256, 0, stream>>>(qb, kb, vt, ao);

  gemm_bt_kernel<1><<<(MTOK/128)*(1024/128), 256, 0, stream>>>(
      ao, wout_t, b_out, out, nullptr, nullptr, nullptr, MTOK, 1024, 1024);
}

// Round 3
// 184.113 us; speedup vs baseline: 1.5649x; 1.5649x over previous
//
#include <hip/hip_runtime.h>
#include <stdint.h>

#define D_MODEL 1024
#define NHEADS 16
#define HDIM 64
#define BATCH 2
#define SEQ 2048
#define MTOK (BATCH*SEQ)

typedef unsigned short u16;
typedef __attribute__((ext_vector_type(8))) __bf16 bf16x8;
typedef __attribute__((ext_vector_type(8))) unsigned short u16x8;
typedef __attribute__((ext_vector_type(4))) unsigned short u16x4;
typedef __attribute__((ext_vector_type(4))) float f32x4;

__device__ __forceinline__ u16 f2bf(float f) {
  union { float f; uint32_t u; } v; v.f = f;
  uint32_t u = v.u;
  u += 0x7fffu + ((u >> 16) & 1u);   // RNE
  return (u16)(u >> 16);
}

__device__ __forceinline__ u16 f2bf_hw(float f) {
  return __builtin_bit_cast(u16, (__bf16)f);   // v_cvt, RNE
}

__device__ __forceinline__ f32x4 max4(f32x4 a, f32x4 b) {
  f32x4 r;
  r[0]=fmaxf(a[0],b[0]); r[1]=fmaxf(a[1],b[1]);
  r[2]=fmaxf(a[2],b[2]); r[3]=fmaxf(a[3],b[3]);
  return r;
}

__device__ __forceinline__ void async16(u16* lds, const u16* g) {
  __builtin_amdgcn_global_load_lds(
      (__attribute__((address_space(1))) void*)(u16*)g,
      (__attribute__((address_space(3))) void*)lds,
      16, 0, 0);
}

// ---------------- cast f32 -> bf16 (vectorized) ----------------
__global__ __launch_bounds__(256) void cast_bf16_kernel(
    const float* __restrict__ in, u16* __restrict__ out, int n8)
{
  int i = blockIdx.x * 256 + threadIdx.x;
  if (i >= n8) return;
  const float4* p = (const float4*)(in + (size_t)i * 8);
  float4 a = p[0], b = p[1];
  u16x8 r;
  r[0]=f2bf(a.x); r[1]=f2bf(a.y); r[2]=f2bf(a.z); r[3]=f2bf(a.w);
  r[4]=f2bf(b.x); r[5]=f2bf(b.y); r[6]=f2bf(b.z); r[7]=f2bf(b.w);
  *(u16x8*)(out + (size_t)i * 8) = r;
}

// ---------------- transpose+cast f32 [R][C] -> bf16 [C][R] ----------------
__global__ __launch_bounds__(256) void transpose_cast_kernel(
    const float* __restrict__ in, u16* __restrict__ out, int R, int C)
{
  __shared__ float tile[32][33];
  int nCB = C >> 5;
  int bc = blockIdx.x % nCB, br = blockIdx.x / nCB;
  int r0 = br * 32, c0 = bc * 32;
  int tx = threadIdx.x & 31, ty = threadIdx.x >> 5;
#pragma unroll
  for (int i = 0; i < 4; ++i)
    tile[ty + i*8][tx] = in[(size_t)(r0 + ty + i*8) * C + c0 + tx];
  __syncthreads();
#pragma unroll
  for (int i = 0; i < 4; ++i)
    out[(size_t)(c0 + ty + i*8) * R + r0 + tx] = f2bf(tile[tx][ty + i*8]);
}

// ---------------- transpose bf16 V [bh][2048][64] -> [bh][64][2048] ----------------
__global__ __launch_bounds__(256) void transpose_v_kernel(
    const u16* __restrict__ vb, u16* __restrict__ vt)
{
  __shared__ u16 tile[32][34];
  int b = blockIdx.x >> 7;      // 0..31 (b*H+h)
  int t = blockIdx.x & 127;
  int br = t >> 1, bc = t & 1;
  int r0 = br * 32, c0 = bc * 32;
  const u16* in = vb + (size_t)b * SEQ * HDIM;
  u16* out = vt + (size_t)b * SEQ * HDIM;
  int tx = threadIdx.x & 31, ty = threadIdx.x >> 5;
#pragma unroll
  for (int i = 0; i < 4; ++i)
    tile[ty + i*8][tx] = in[(size_t)(r0 + ty + i*8) * HDIM + c0 + tx];
  __syncthreads();
#pragma unroll
  for (int i = 0; i < 4; ++i)
    out[(size_t)(c0 + ty + i*8) * SEQ + r0 + tx] = tile[tx][ty + i*8];
}

// ---------------- NT GEMM: C[M][N] = A[M][K](bf16) * Bt[N][K](bf16)^T + bias ----------------
// EPI=0: QKV epilogue -> scatter q(*scale*log2e)/k/v into [B,H,N,Hd] bf16
// EPI=1: f32 out
template <int EPI>
__global__ __launch_bounds__(256) void gemm_bt_kernel(
    const u16* __restrict__ A, const u16* __restrict__ Bt,
    const float* __restrict__ bias,
    float* __restrict__ outF,
    u16* __restrict__ qb, u16* __restrict__ kb, u16* __restrict__ vb,
    int M, int Nn, int K)
{
  __shared__ alignas(16) u16 As[128 * 64];
  __shared__ alignas(16) u16 Bs[128 * 64];

  const int tid = threadIdx.x;
  const int wid = tid >> 6, lane = tid & 63;
  const int col = lane & 15, kg = lane >> 4;

  const int nTN = Nn >> 7;
  int bidx = blockIdx.x;
  {
    int cpx = gridDim.x >> 3;     // grid % 8 == 0 for all our launches
    bidx = (bidx & 7) * cpx + (bidx >> 3);
  }
  const int tile_m = (bidx / nTN) << 7;
  const int tile_n = (bidx % nTN) << 7;
  const int wm = (wid >> 1) << 6, wn = (wid & 1) << 6;

  f32x4 acc[4][4] = {};

  const int sr = tid >> 3;          // 0..31
  const int sc = (tid & 7) << 3;    // 0..56

  for (int kt = 0; kt < K; kt += 64) {
    __syncthreads();
#pragma unroll
    for (int i = 0; i < 4; ++i)
      async16(&As[(i*32 + sr) * 64 + sc],
              A + (size_t)(tile_m + i*32 + sr) * K + kt + sc);
#pragma unroll
    for (int i = 0; i < 4; ++i)
      async16(&Bs[(i*32 + sr) * 64 + sc],
              Bt + (size_t)(tile_n + i*32 + sr) * K + kt + sc);
    __syncthreads();

#pragma unroll
    for (int ks = 0; ks < 2; ++ks) {
      bf16x8 af[4], bfv[4];
#pragma unroll
      for (int i = 0; i < 4; ++i)
        af[i] = *(const bf16x8*)&As[(wm + i*16 + col) * 64 + ks*32 + kg*8];
#pragma unroll
      for (int i = 0; i < 4; ++i)
        bfv[i] = *(const bf16x8*)&Bs[(wn + i*16 + col) * 64 + ks*32 + kg*8];
#pragma unroll
      for (int i = 0; i < 4; ++i)
#pragma unroll
        for (int j = 0; j < 4; ++j)
          acc[i][j] = __builtin_amdgcn_mfma_f32_16x16x32_bf16(af[i], bfv[j], acc[i][j], 0, 0, 0);
    }
  }

  // epilogue: lane holds C[tile_m+wm+i*16+kg*4+j][tile_n+wn+jn*16+col]
#pragma unroll
  for (int i = 0; i < 4; ++i) {
#pragma unroll
    for (int jn = 0; jn < 4; ++jn) {
      const int gcol = tile_n + wn + jn*16 + col;
      const float bv = bias[gcol];
#pragma unroll
      for (int j = 0; j < 4; ++j) {
        const int grow = tile_m + wm + i*16 + kg*4 + j;
        float val = acc[i][jn][j] + bv;
        if (EPI == 1) {
          outF[(size_t)grow * Nn + gcol] = val;
        } else {
          int btok = grow >> 11, tok = grow & 2047;
          int which = gcol >> 10, f = gcol & 1023;
          int h = f >> 6, hd = f & 63;
          size_t dst = ((size_t)(btok * NHEADS + h) * SEQ + tok) * HDIM + hd;
          // fold scale = Hd^-0.5 * log2(e) into Q (softmax runs in exp2 domain)
          if (which == 0)      qb[dst] = f2bf(val * 0.18033688f);
          else if (which == 1) kb[dst] = f2bf(val);
          else                 vb[dst] = f2bf(val);
        }
      }
    }
  }
}

// ---------------- flash attention: staged K/V, swapped-operand softmax ----------------
// block = (b*H+h, q-tile of 128); 4 waves x 32 q-rows; KV tile = 128.
// QK^T computed swapped (S^T = K·Q^T) so each lane owns q=col with 32 k-values
// in-register -> softmax is an in-lane tree + 2 shuffles. PV computed swapped
// (O^T = V^T·P^T) so rescale/denominator stay lane-local.
__global__ __launch_bounds__(256) void attn_kernel(
    const u16* __restrict__ qb, const u16* __restrict__ kb,
    const u16* __restrict__ vt, u16* __restrict__ ao)
{
  __shared__ alignas(16) u16 Ks[128 * 72];     // [kv 128][hd 64] pitch 72
  __shared__ alignas(16) u16 Vs[64 * 136];     // [hd 64][kv 128] pitch 136
  __shared__ alignas(16) u16 Pl[4][32 * 136];  // per-wave P [32 q][128 kv] pitch 136

  const int tid = threadIdx.x, wid = tid >> 6, lane = tid & 63;
  const int col = lane & 15, kg = lane >> 4;

  int bidx = blockIdx.x;
  bidx = (bidx & 7) * 64 + (bidx >> 3);   // XCD swizzle (grid 512)
  const int bh = bidx >> 4;     // 0..31
  const int qt = bidx & 15;

  const u16* Qh = qb + (size_t)bh * SEQ * HDIM;
  const u16* Kh = kb + (size_t)bh * SEQ * HDIM;
  const u16* Vh = vt + (size_t)bh * SEQ * HDIM;  // [64][2048]

  const int q0 = qt * 128 + wid * 32;
  // Q as B-operand: lane holds Q[q = mf*16+col][d = ks*32+kg*8 .. +7]
  bf16x8 qf[2][2];
#pragma unroll
  for (int mf = 0; mf < 2; ++mf)
#pragma unroll
    for (int ks = 0; ks < 2; ++ks)
      qf[mf][ks] = *(const bf16x8*)(Qh + (size_t)(q0 + mf*16 + col) * HDIM + ks*32 + kg*8);

  float m_run[2] = {-1e30f, -1e30f};
  float l_run[2] = {0.f, 0.f};
  f32x4 o[2][4] = {};   // O^T[hd = hf*16+kg*4+j][q = mf*16+col]

  u16* Pw = Pl[wid];

  for (int t = 0; t < 16; ++t) {
    __syncthreads();
    // stage K tile [128][64]
#pragma unroll
    for (int i = 0; i < 4; ++i) {
      int idx = i*256 + tid;
      int r = idx >> 3, c8 = (idx & 7) << 3;
      *(u16x8*)&Ks[r * 72 + c8] = *(const u16x8*)(Kh + (size_t)(t*128 + r) * HDIM + c8);
    }
    // stage V^T tile [64][128] from globally-transposed V
#pragma unroll
    for (int i = 0; i < 4; ++i) {
      int idx = i*256 + tid;
      int hd = idx >> 4, c8 = (idx & 15) << 3;
      *(u16x8*)&Vs[hd * 136 + c8] = *(const u16x8*)(Vh + (size_t)hd * SEQ + t*128 + c8);
    }
    __syncthreads();

    // S^T = K Q^T : s[mf][nf] rows k = nf*16+kg*4+r, col q = mf*16+col
    f32x4 s[2][8] = {};
#pragma unroll
    for (int ks = 0; ks < 2; ++ks) {
#pragma unroll
      for (int nf = 0; nf < 8; ++nf) {
        bf16x8 kf = *(const bf16x8*)&Ks[(nf*16 + col) * 72 + ks*32 + kg*8];
        s[0][nf] = __builtin_amdgcn_mfma_f32_16x16x32_bf16(kf, qf[0][ks], s[0][nf], 0, 0, 0);
        s[1][nf] = __builtin_amdgcn_mfma_f32_16x16x32_bf16(kf, qf[1][ks], s[1][nf], 0, 0, 0);
      }
    }

    // online softmax (exp2 domain), lane-local per q
#pragma unroll
    for (int mf = 0; mf < 2; ++mf) {
      // max tree over 32 in-lane values
      f32x4 t0 = max4(s[mf][0], s[mf][1]);
      f32x4 t1 = max4(s[mf][2], s[mf][3]);
      f32x4 t2 = max4(s[mf][4], s[mf][5]);
      f32x4 t3 = max4(s[mf][6], s[mf][7]);
      f32x4 u0 = max4(max4(t0, t1), max4(t2, t3));
      float mx = fmaxf(fmaxf(u0[0], u0[1]), fmaxf(u0[2], u0[3]));
      // cross-kg reduce (lanes col, col+16, col+32, col+48 share q)
      mx = fmaxf(mx, __shfl_xor(mx, 16));
      mx = fmaxf(mx, __shfl_xor(mx, 32));
      float mo = m_run[mf];
      float mn = fmaxf(mo, mx);
      float al = __builtin_amdgcn_exp2f(mo - mn);
      m_run[mf] = mn;
      // exp + sum
      f32x4 sum4 = {0.f, 0.f, 0.f, 0.f};
#pragma unroll
      for (int nf = 0; nf < 8; ++nf) {
#pragma unroll
        for (int r = 0; r < 4; ++r)
          s[mf][nf][r] = __builtin_amdgcn_exp2f(s[mf][nf][r] - mn);
        sum4[0] += s[mf][nf][0]; sum4[1] += s[mf][nf][1];
        sum4[2] += s[mf][nf][2]; sum4[3] += s[mf][nf][3];
      }
      float sum = (sum4[0] + sum4[1]) + (sum4[2] + sum4[3]);
      sum += __shfl_xor(sum, 16);
      sum += __shfl_xor(sum, 32);
      l_run[mf] = l_run[mf] * al + sum;
      // rescale O column (lane-local q)
#pragma unroll
      for (int hf = 0; hf < 4; ++hf)
#pragma unroll
        for (int j = 0; j < 4; ++j) o[mf][hf][j] *= al;
      // pack P -> LDS: P[q = mf*16+col][k = nf*16+kg*4 .. +3], one b64 per nf
#pragma unroll
      for (int nf = 0; nf < 8; ++nf) {
        u16x4 pk;
        pk[0] = f2bf_hw(s[mf][nf][0]); pk[1] = f2bf_hw(s[mf][nf][1]);
        pk[2] = f2bf_hw(s[mf][nf][2]); pk[3] = f2bf_hw(s[mf][nf][3]);
        *(u16x4*)&Pw[(mf*16 + col) * 136 + nf*16 + kg*4] = pk;
      }
    }

    // O^T += V^T P^T
#pragma unroll
    for (int ks = 0; ks < 4; ++ks) {
      bf16x8 pf0 = *(const bf16x8*)&Pw[(col) * 136 + ks*32 + kg*8];
      bf16x8 pf1 = *(const bf16x8*)&Pw[(16 + col) * 136 + ks*32 + kg*8];
#pragma unroll
      for (int hf = 0; hf < 4; ++hf) {
        bf16x8 vf = *(const bf16x8*)&Vs[(hf*16 + col) * 136 + ks*32 + kg*8];
        o[0][hf] = __builtin_amdgcn_mfma_f32_16x16x32_bf16(vf, pf0, o[0][hf], 0, 0, 0);
        o[1][hf] = __builtin_amdgcn_mfma_f32_16x16x32_bf16(vf, pf1, o[1][hf], 0, 0, 0);
      }
    }
  }

  // epilogue: O^T/l -> ao[token][h*64+hd] bf16 (lane-local l), b64 stores
  const int bb = bh >> 4, h = bh & 15;
#pragma unroll
  for (int mf = 0; mf < 2; ++mf) {
    float inv = 1.0f / l_run[mf];
    int nrow = q0 + mf*16 + col;
#pragma unroll
    for (int hf = 0; hf < 4; ++hf) {
      u16x4 pk;
#pragma unroll
      for (int j = 0; j < 4; ++j) pk[j] = f2bf(o[mf][hf][j] * inv);
      int feat = h*64 + hf*16 + kg*4;
      *(u16x4*)&ao[(size_t)(bb * SEQ + nrow) * D_MODEL + feat] = pk;
    }
  }
}

extern "C" void kernel_launch(void* const* d_in, const int* in_sizes, int n_in,
                              void* d_out, int out_size, void* d_ws, size_t ws_size,
                              hipStream_t stream)
{
  const float* x     = (const float*)d_in[0];
  const float* w_qkv = (const float*)d_in[1];
  const float* b_qkv = (const float*)d_in[2];
  const float* w_out = (const float*)d_in[3];
  const float* b_out = (const float*)d_in[4];
  float* out = (float*)d_out;
  (void)in_sizes; (void)n_in; (void)out_size; (void)ws_size;

  char* ws = (char*)d_ws;
  u16* x_bf   = (u16*)(ws);                        // 8 MB  [4096][1024]
  u16* wqkv_t = (u16*)(ws + (size_t)( 8 << 20));   // 6 MB  [3072][1024]
  u16* wout_t = (u16*)(ws + (size_t)(14 << 20));   // 2 MB  [1024][1024]
  u16* qb     = (u16*)(ws + (size_t)(16 << 20));   // 8 MB  [32][2048][64]
  u16* kb     = (u16*)(ws + (size_t)(24 << 20));   // 8 MB
  u16* vb     = (u16*)(ws + (size_t)(32 << 20));   // 8 MB
  u16* vt     = (u16*)(ws + (size_t)(40 << 20));   // 8 MB  [32][64][2048]
  u16* ao     = (u16*)(ws + (size_t)(48 << 20));   // 8 MB  [4096][1024]

  cast_bf16_kernel<<<2048, 256, 0, stream>>>(x, x_bf, (MTOK * D_MODEL) / 8);
  transpose_cast_kernel<<<(1024/32)*(3072/32), 256, 0, stream>>>(w_qkv, wqkv_t, 1024, 3072);
  transpose_cast_kernel<<<(1024/32)*(1024/32), 256, 0, stream>>>(w_out, wout_t, 1024, 1024);

  gemm_bt_kernel<0><<<(MTOK/128)*(3072/128), 256, 0, stream>>>(
      x_bf, wqkv_t, b_qkv, nullptr, qb, kb, vb, MTOK, 3072, 1024);

  transpose_v_kernel<<<32*128, 256, 0, stream>>>(vb, vt);

  attn_kernel<<<32*16, 256, 0, stream>>>(qb, kb, vt, ao);

  gemm_bt_kernel<1><<<(MTOK/128)*(1024/128), 256, 0, stream>>>(
      ao, wout_t, b_out, out, nullptr, nullptr, nullptr, MTOK, 1024, 1024);
}

// Round 4
// 172.455 us; speedup vs baseline: 1.6706x; 1.0676x over previous
//
#include <hip/hip_runtime.h>
#include <stdint.h>

#define D_MODEL 1024
#define NHEADS 16
#define HDIM 64
#define BATCH 2
#define SEQ 2048
#define MTOK (BATCH*SEQ)

typedef unsigned short u16;
typedef __attribute__((ext_vector_type(8))) __bf16 bf16x8;
typedef __attribute__((ext_vector_type(8))) unsigned short u16x8;
typedef __attribute__((ext_vector_type(4))) unsigned short u16x4;
typedef __attribute__((ext_vector_type(4))) float f32x4;

__device__ __forceinline__ u16 f2bf(float f) {
  union { float f; uint32_t u; } v; v.f = f;
  uint32_t u = v.u;
  u += 0x7fffu + ((u >> 16) & 1u);   // RNE
  return (u16)(u >> 16);
}

__device__ __forceinline__ u16 f2bf_hw(float f) {
  return __builtin_bit_cast(u16, (__bf16)f);   // v_cvt, RNE
}

__device__ __forceinline__ f32x4 max4(f32x4 a, f32x4 b) {
  f32x4 r;
  r[0]=fmaxf(a[0],b[0]); r[1]=fmaxf(a[1],b[1]);
  r[2]=fmaxf(a[2],b[2]); r[3]=fmaxf(a[3],b[3]);
  return r;
}

__device__ __forceinline__ void async16(u16* lds, const u16* g) {
  __builtin_amdgcn_global_load_lds(
      (__attribute__((address_space(1))) void*)(u16*)g,
      (__attribute__((address_space(3))) void*)lds,
      16, 0, 0);
}

// ---------------- cast f32 -> bf16 (vectorized) ----------------
__global__ __launch_bounds__(256) void cast_bf16_kernel(
    const float* __restrict__ in, u16* __restrict__ out, int n8)
{
  int i = blockIdx.x * 256 + threadIdx.x;
  if (i >= n8) return;
  const float4* p = (const float4*)(in + (size_t)i * 8);
  float4 a = p[0], b = p[1];
  u16x8 r;
  r[0]=f2bf(a.x); r[1]=f2bf(a.y); r[2]=f2bf(a.z); r[3]=f2bf(a.w);
  r[4]=f2bf(b.x); r[5]=f2bf(b.y); r[6]=f2bf(b.z); r[7]=f2bf(b.w);
  *(u16x8*)(out + (size_t)i * 8) = r;
}

// ---------------- transpose+cast f32 [R][C] -> bf16 [C][R] ----------------
__global__ __launch_bounds__(256) void transpose_cast_kernel(
    const float* __restrict__ in, u16* __restrict__ out, int R, int C)
{
  __shared__ float tile[32][33];
  int nCB = C >> 5;
  int bc = blockIdx.x % nCB, br = blockIdx.x / nCB;
  int r0 = br * 32, c0 = bc * 32;
  int tx = threadIdx.x & 31, ty = threadIdx.x >> 5;
#pragma unroll
  for (int i = 0; i < 4; ++i)
    tile[ty + i*8][tx] = in[(size_t)(r0 + ty + i*8) * C + c0 + tx];
  __syncthreads();
#pragma unroll
  for (int i = 0; i < 4; ++i)
    out[(size_t)(c0 + ty + i*8) * R + r0 + tx] = f2bf(tile[tx][ty + i*8]);
}

// ---------------- transpose bf16 V [bh][2048][64] -> [bh][64][2048] ----------------
__global__ __launch_bounds__(256) void transpose_v_kernel(
    const u16* __restrict__ vb, u16* __restrict__ vt)
{
  __shared__ u16 tile[32][34];
  int b = blockIdx.x >> 7;      // 0..31 (b*H+h)
  int t = blockIdx.x & 127;
  int br = t >> 1, bc = t & 1;
  int r0 = br * 32, c0 = bc * 32;
  const u16* in = vb + (size_t)b * SEQ * HDIM;
  u16* out = vt + (size_t)b * SEQ * HDIM;
  int tx = threadIdx.x & 31, ty = threadIdx.x >> 5;
#pragma unroll
  for (int i = 0; i < 4; ++i)
    tile[ty + i*8][tx] = in[(size_t)(r0 + ty + i*8) * HDIM + c0 + tx];
  __syncthreads();
#pragma unroll
  for (int i = 0; i < 4; ++i)
    out[(size_t)(c0 + ty + i*8) * SEQ + r0 + tx] = tile[tx][ty + i*8];
}

// ---------------- NT GEMM: C[M][N] = A[M][K](bf16) * Bt[N][K](bf16)^T + bias ----------------
// EPI=0: QKV epilogue -> scatter q(*scale*log2e)/k/v into [B,H,N,Hd] bf16
// EPI=1: f32 out
template <int EPI>
__global__ __launch_bounds__(256) void gemm_bt_kernel(
    const u16* __restrict__ A, const u16* __restrict__ Bt,
    const float* __restrict__ bias,
    float* __restrict__ outF,
    u16* __restrict__ qb, u16* __restrict__ kb, u16* __restrict__ vb,
    int M, int Nn, int K)
{
  __shared__ alignas(16) u16 As[128 * 64];
  __shared__ alignas(16) u16 Bs[128 * 64];

  const int tid = threadIdx.x;
  const int wid = tid >> 6, lane = tid & 63;
  const int col = lane & 15, kg = lane >> 4;

  const int nTN = Nn >> 7;
  int bidx = blockIdx.x;
  {
    int cpx = gridDim.x >> 3;     // grid % 8 == 0 for all our launches
    bidx = (bidx & 7) * cpx + (bidx >> 3);
  }
  const int tile_m = (bidx / nTN) << 7;
  const int tile_n = (bidx % nTN) << 7;
  const int wm = (wid >> 1) << 6, wn = (wid & 1) << 6;

  f32x4 acc[4][4] = {};

  const int sr = tid >> 3;          // 0..31
  const int sc = (tid & 7) << 3;    // 0..56

  for (int kt = 0; kt < K; kt += 64) {
    __syncthreads();
#pragma unroll
    for (int i = 0; i < 4; ++i)
      async16(&As[(i*32 + sr) * 64 + sc],
              A + (size_t)(tile_m + i*32 + sr) * K + kt + sc);
#pragma unroll
    for (int i = 0; i < 4; ++i)
      async16(&Bs[(i*32 + sr) * 64 + sc],
              Bt + (size_t)(tile_n + i*32 + sr) * K + kt + sc);
    __syncthreads();

#pragma unroll
    for (int ks = 0; ks < 2; ++ks) {
      bf16x8 af[4], bfv[4];
#pragma unroll
      for (int i = 0; i < 4; ++i)
        af[i] = *(const bf16x8*)&As[(wm + i*16 + col) * 64 + ks*32 + kg*8];
#pragma unroll
      for (int i = 0; i < 4; ++i)
        bfv[i] = *(const bf16x8*)&Bs[(wn + i*16 + col) * 64 + ks*32 + kg*8];
#pragma unroll
      for (int i = 0; i < 4; ++i)
#pragma unroll
        for (int j = 0; j < 4; ++j)
          acc[i][j] = __builtin_amdgcn_mfma_f32_16x16x32_bf16(af[i], bfv[j], acc[i][j], 0, 0, 0);
    }
  }

  // epilogue: lane holds C[tile_m+wm+i*16+kg*4+j][tile_n+wn+jn*16+col]
#pragma unroll
  for (int i = 0; i < 4; ++i) {
#pragma unroll
    for (int jn = 0; jn < 4; ++jn) {
      const int gcol = tile_n + wn + jn*16 + col;
      const float bv = bias[gcol];
#pragma unroll
      for (int j = 0; j < 4; ++j) {
        const int grow = tile_m + wm + i*16 + kg*4 + j;
        float val = acc[i][jn][j] + bv;
        if (EPI == 1) {
          outF[(size_t)grow * Nn + gcol] = val;
        } else {
          int btok = grow >> 11, tok = grow & 2047;
          int which = gcol >> 10, f = gcol & 1023;
          int h = f >> 6, hd = f & 63;
          size_t dst = ((size_t)(btok * NHEADS + h) * SEQ + tok) * HDIM + hd;
          // fold scale = Hd^-0.5 * log2(e) into Q (softmax runs in exp2 domain)
          if (which == 0)      qb[dst] = f2bf(val * 0.18033688f);
          else if (which == 1) kb[dst] = f2bf(val);
          else                 vb[dst] = f2bf(val);
        }
      }
    }
  }
}

// ---------------- flash attention: QBLK=64, reg-prefetch staging, swapped softmax ----------------
// block = (b*H+h, q-tile of 64); 4 waves x 16 q-rows; KV tile = 128; 3 blocks/CU.
// S^T = K·Q^T so lane owns q=col with 32 k in-register; O^T = V^T·P^T keeps
// rescale/denominator lane-local. K/V tile t+1 is loaded into registers during
// compute of tile t (T14 async-stage) and written to LDS after the barrier.
__global__ __launch_bounds__(256, 3) void attn_kernel(
    const u16* __restrict__ qb, const u16* __restrict__ kb,
    const u16* __restrict__ vt, u16* __restrict__ ao)
{
  __shared__ alignas(16) u16 Ks[128 * 72];     // [kv 128][hd 64] pitch 72
  __shared__ alignas(16) u16 Vs[64 * 136];     // [hd 64][kv 128] pitch 136
  __shared__ alignas(16) u16 Pl[4][16 * 136];  // per-wave P [16 q][128 kv] pitch 136

  const int tid = threadIdx.x, wid = tid >> 6, lane = tid & 63;
  const int col = lane & 15, kg = lane >> 4;

  int bidx = blockIdx.x;
  bidx = (bidx & 7) * 128 + (bidx >> 3);   // XCD swizzle (grid 1024)
  const int bh = bidx >> 5;     // 0..31   (32 q-tiles per bh -> same XCD)
  const int qt = bidx & 31;

  const u16* Qh = qb + (size_t)bh * SEQ * HDIM;
  const u16* Kh = kb + (size_t)bh * SEQ * HDIM;
  const u16* Vh = vt + (size_t)bh * SEQ * HDIM;  // [64][2048]

  const int q0 = qt * 64 + wid * 16;
  // Q as B-operand: lane holds Q[q = col][d = ks*32+kg*8 .. +7]
  bf16x8 qf[2];
#pragma unroll
  for (int ks = 0; ks < 2; ++ks)
    qf[ks] = *(const bf16x8*)(Qh + (size_t)(q0 + col) * HDIM + ks*32 + kg*8);

  float m_run = -1e30f, l_run = 0.f;
  f32x4 o[4] = {};   // O^T[hd = hf*16+kg*4+j][q = col]

  u16* Pw = Pl[wid];

  // staging geometry (whole block covers K tile [128][64], V^T tile [64][128])
  const int krow = tid >> 3;            // 0..31
  const int kcol = (tid & 7) << 3;      // u16 units
  const int vrow = tid >> 4;            // 0..15
  const int vcol = (tid & 15) << 3;

  u16x8 kreg[4], vreg[4];
#define LOAD_TILES(t)                                                          \
  {                                                                            \
    _Pragma("unroll")                                                          \
    for (int i = 0; i < 4; ++i)                                                \
      kreg[i] = *(const u16x8*)(Kh + (size_t)((t)*128 + i*32 + krow) * HDIM + kcol); \
    _Pragma("unroll")                                                          \
    for (int i = 0; i < 4; ++i)                                                \
      vreg[i] = *(const u16x8*)(Vh + (size_t)(i*16 + vrow) * SEQ + (t)*128 + vcol);  \
  }

  LOAD_TILES(0);

  for (int t = 0; t < 16; ++t) {
    __syncthreads();   // previous tile's LDS reads done
#pragma unroll
    for (int i = 0; i < 4; ++i)
      *(u16x8*)&Ks[(i*32 + krow) * 72 + kcol] = kreg[i];
#pragma unroll
    for (int i = 0; i < 4; ++i)
      *(u16x8*)&Vs[(i*16 + vrow) * 136 + vcol] = vreg[i];
    __syncthreads();
    if (t < 15) LOAD_TILES(t + 1);   // async: latency hides under compute below

    // S^T = K Q^T : s[nf] rows k = nf*16+kg*4+r, col q = col
    f32x4 s[8] = {};
#pragma unroll
    for (int ks = 0; ks < 2; ++ks) {
#pragma unroll
      for (int nf = 0; nf < 8; ++nf) {
        bf16x8 kf = *(const bf16x8*)&Ks[(nf*16 + col) * 72 + ks*32 + kg*8];
        s[nf] = __builtin_amdgcn_mfma_f32_16x16x32_bf16(kf, qf[ks], s[nf], 0, 0, 0);
      }
    }

    // online softmax (exp2 domain), lane-local per q
    {
      f32x4 t0 = max4(s[0], s[1]);
      f32x4 t1 = max4(s[2], s[3]);
      f32x4 t2 = max4(s[4], s[5]);
      f32x4 t3 = max4(s[6], s[7]);
      f32x4 u0 = max4(max4(t0, t1), max4(t2, t3));
      float mx = fmaxf(fmaxf(u0[0], u0[1]), fmaxf(u0[2], u0[3]));
      mx = fmaxf(mx, __shfl_xor(mx, 16));
      mx = fmaxf(mx, __shfl_xor(mx, 32));
      float mo = m_run;
      float mn = fmaxf(mo, mx);
      float al = __builtin_amdgcn_exp2f(mo - mn);
      m_run = mn;
      f32x4 sum4 = {0.f, 0.f, 0.f, 0.f};
#pragma unroll
      for (int nf = 0; nf < 8; ++nf) {
#pragma unroll
        for (int r = 0; r < 4; ++r)
          s[nf][r] = __builtin_amdgcn_exp2f(s[nf][r] - mn);
        sum4[0] += s[nf][0]; sum4[1] += s[nf][1];
        sum4[2] += s[nf][2]; sum4[3] += s[nf][3];
      }
      float sum = (sum4[0] + sum4[1]) + (sum4[2] + sum4[3]);
      sum += __shfl_xor(sum, 16);
      sum += __shfl_xor(sum, 32);
      l_run = l_run * al + sum;
#pragma unroll
      for (int hf = 0; hf < 4; ++hf)
#pragma unroll
        for (int j = 0; j < 4; ++j) o[hf][j] *= al;
      // pack P -> LDS: P[q = col][k = nf*16+kg*4 .. +3]
#pragma unroll
      for (int nf = 0; nf < 8; ++nf) {
        u16x4 pk;
        pk[0] = f2bf_hw(s[nf][0]); pk[1] = f2bf_hw(s[nf][1]);
        pk[2] = f2bf_hw(s[nf][2]); pk[3] = f2bf_hw(s[nf][3]);
        *(u16x4*)&Pw[col * 136 + nf*16 + kg*4] = pk;
      }
    }

    // O^T += V^T P^T
#pragma unroll
    for (int ks = 0; ks < 4; ++ks) {
      bf16x8 pf = *(const bf16x8*)&Pw[col * 136 + ks*32 + kg*8];
#pragma unroll
      for (int hf = 0; hf < 4; ++hf) {
        bf16x8 vf = *(const bf16x8*)&Vs[(hf*16 + col) * 136 + ks*32 + kg*8];
        o[hf] = __builtin_amdgcn_mfma_f32_16x16x32_bf16(vf, pf, o[hf], 0, 0, 0);
      }
    }
  }

  // epilogue: O^T/l -> ao[token][h*64+hd] bf16 (lane-local l), b64 stores
  const int bb = bh >> 4, h = bh & 15;
  {
    float inv = 1.0f / l_run;
    int nrow = q0 + col;
#pragma unroll
    for (int hf = 0; hf < 4; ++hf) {
      u16x4 pk;
#pragma unroll
      for (int j = 0; j < 4; ++j) pk[j] = f2bf(o[hf][j] * inv);
      int feat = h*64 + hf*16 + kg*4;
      *(u16x4*)&ao[(size_t)(bb * SEQ + nrow) * D_MODEL + feat] = pk;
    }
  }
#undef LOAD_TILES
}

extern "C" void kernel_launch(void* const* d_in, const int* in_sizes, int n_in,
                              void* d_out, int out_size, void* d_ws, size_t ws_size,
                              hipStream_t stream)
{
  const float* x     = (const float*)d_in[0];
  const float* w_qkv = (const float*)d_in[1];
  const float* b_qkv = (const float*)d_in[2];
  const float* w_out = (const float*)d_in[3];
  const float* b_out = (const float*)d_in[4];
  float* out = (float*)d_out;
  (void)in_sizes; (void)n_in; (void)out_size; (void)ws_size;

  char* ws = (char*)d_ws;
  u16* x_bf   = (u16*)(ws);                        // 8 MB  [4096][1024]
  u16* wqkv_t = (u16*)(ws + (size_t)( 8 << 20));   // 6 MB  [3072][1024]
  u16* wout_t = (u16*)(ws + (size_t)(14 << 20));   // 2 MB  [1024][1024]
  u16* qb     = (u16*)(ws + (size_t)(16 << 20));   // 8 MB  [32][2048][64]
  u16* kb     = (u16*)(ws + (size_t)(24 << 20));   // 8 MB
  u16* vb     = (u16*)(ws + (size_t)(32 << 20));   // 8 MB
  u16* vt     = (u16*)(ws + (size_t)(40 << 20));   // 8 MB  [32][64][2048]
  u16* ao     = (u16*)(ws + (size_t)(48 << 20));   // 8 MB  [4096][1024]

  cast_bf16_kernel<<<2048, 256, 0, stream>>>(x, x_bf, (MTOK * D_MODEL) / 8);
  transpose_cast_kernel<<<(1024/32)*(3072/32), 256, 0, stream>>>(w_qkv, wqkv_t, 1024, 3072);
  transpose_cast_kernel<<<(1024/32)*(1024/32), 256, 0, stream>>>(w_out, wout_t, 1024, 1024);

  gemm_bt_kernel<0><<<(MTOK/128)*(3072/128), 256, 0, stream>>>(
      x_bf, wqkv_t, b_qkv, nullptr, qb, kb, vb, MTOK, 3072, 1024);

  transpose_v_kernel<<<32*128, 256, 0, stream>>>(vb, vt);

  attn_kernel<<<32*32, 256, 0, stream>>>(qb, kb, vt, ao);

  gemm_bt_kernel<1><<<(MTOK/128)*(1024/128), 256, 0, stream>>>(
      ao, wout_t, b_out, out, nullptr, nullptr, nullptr, MTOK, 1024, 1024);
}